// Round 7
// baseline (736.214 us; speedup 1.0000x reference)
//
#include <hip/hip_runtime.h>
#include <stdint.h>

#define H_DIM 4096
#define I_DIM 11008
#define T_DIM 4096

typedef int i32x4 __attribute__((ext_vector_type(4)));
typedef const void __attribute__((address_space(1))) gvoid_t;
typedef void __attribute__((address_space(3))) svoid_t;

__device__ __forceinline__ void gload_lds16(const void* gsrc, void* ldst) {
    __builtin_amdgcn_global_load_lds((gvoid_t*)gsrc, (svoid_t*)ldst, 16, 0, 0);
}
__device__ __forceinline__ void wait_vmcnt6() {
    asm volatile("s_waitcnt vmcnt(6)" ::: "memory");
}
__device__ __forceinline__ void wait_vmcnt12() {
    asm volatile("s_waitcnt vmcnt(12)" ::: "memory");
}
__device__ __forceinline__ void wait_vmcnt0() {
    asm volatile("s_waitcnt vmcnt(0)" ::: "memory");
}
__device__ __forceinline__ void wait_lgkm0() {
    asm volatile("s_waitcnt lgkmcnt(0)" ::: "memory");
    __builtin_amdgcn_sched_barrier(0);
}
__device__ __forceinline__ void barrier_() {
    asm volatile("s_barrier" ::: "memory");
}

__device__ __forceinline__ uint32_t pack4(int4 v) {
    uint32_t r = (uint32_t)(uint8_t)v.x;
    r |= (uint32_t)(uint8_t)v.y << 8;
    r |= (uint32_t)(uint8_t)v.z << 16;
    r |= (uint32_t)(uint8_t)v.w << 24;
    return r;
}

// int32 -> int8 pack (truncate low byte; values already int8-range)
__global__ void convert_kernel(const int* __restrict__ src, int8_t* __restrict__ dst,
                               int n4) {
    int idx = blockIdx.x * blockDim.x + threadIdx.x;
    int stride = gridDim.x * blockDim.x;
    for (int i = idx; i < n4; i += stride) {
        int4 v = ((const int4*)src)[i];
        ((uint32_t*)dst)[i] = pack4(v);
    }
}

#define MFMA_I8 __builtin_amdgcn_mfma_i32_16x16x64_i8

// ---------------------------------------------------------------------------
// gateup: BM=128 BN=128 BK=64B, 4 waves (2Mx2N), wave = 64x64 (G and U accs).
// 3-buffer LDS pipeline, ONE barrier per K-step, register-double-buffered
// fragments: ds_read(t+1) co-issues under MFMA(t). Counted vmcnt(6) with a
// 2-step staging lead. XOR-swizzled LDS (verified 0-conflict).
// ---------------------------------------------------------------------------
__global__ __launch_bounds__(256, 2)
void gateup_kernel(const int8_t* __restrict__ x8, const int8_t* __restrict__ gw8,
                   const int8_t* __restrict__ uw8,
                   const float* __restrict__ galpha, const float* __restrict__ gbias,
                   const float* __restrict__ ualpha, const float* __restrict__ ubias,
                   const float* __restrict__ scale_p, int8_t* __restrict__ hq)
{
    __shared__ __align__(16) int8_t lsA[3][128 * 64];
    __shared__ __align__(16) int8_t lsG[3][128 * 64];
    __shared__ __align__(16) int8_t lsU[3][128 * 64];

    const int bid = blockIdx.x;
    const int mt = bid & 31;                   // M fastest: 32 blocks share G/U tiles in L2
    const int nt = bid >> 5;
    const int m0 = mt << 7;
    const int n0 = nt << 7;

    const int tid  = threadIdx.x;
    const int lane = tid & 63;
    const int wid  = tid >> 6;                 // 0..3
    const int wr   = wid >> 1;
    const int wc   = wid & 1;
    const int lr   = lane & 15;
    const int rdsw = ((lane >> 4) ^ ((lr >> 1) & 3)) << 4;  // read-side XOR slot

    const int srow = tid >> 2;                           // 0..63
    const int scol = ((tid & 3) ^ ((tid >> 3) & 3)) << 4;
    const int woff = wid << 10;

    const int8_t* As = x8  + (size_t)(m0 + srow) * H_DIM + scol;
    const int8_t* Gs = gw8 + (size_t)(n0 + srow) * H_DIM + scol;
    const int8_t* Us = uw8 + (size_t)(n0 + srow) * H_DIM + scol;

    i32x4 accg[4][4], accu[4][4];
#pragma unroll
    for (int mf = 0; mf < 4; ++mf)
#pragma unroll
        for (int nf = 0; nf < 4; ++nf) {
            accg[mf][nf] = i32x4{0, 0, 0, 0};
            accu[mf][nf] = i32x4{0, 0, 0, 0};
        }

    const int aro = (wr * 64 + lr) * 64 + rdsw;    // + mf*1024
    const int gro = (wc * 64 + lr) * 64 + rdsw;    // + nf*1024

#define STAGE_GU(b, kb) do { \
        gload_lds16(As + (kb),                        &lsA[b][woff]); \
        gload_lds16(As + (kb) + (size_t)64 * H_DIM,   &lsA[b][4096 + woff]); \
        gload_lds16(Gs + (kb),                        &lsG[b][woff]); \
        gload_lds16(Gs + (kb) + (size_t)64 * H_DIM,   &lsG[b][4096 + woff]); \
        gload_lds16(Us + (kb),                        &lsU[b][woff]); \
        gload_lds16(Us + (kb) + (size_t)64 * H_DIM,   &lsU[b][4096 + woff]); \
    } while (0)

#define RD_GU(AF, BG, BU, tt) do { \
        const int _b = (tt) % 3; \
        _Pragma("unroll") for (int mf = 0; mf < 4; ++mf) \
            AF[mf] = *(const i32x4*)&lsA[_b][aro + mf * 1024]; \
        _Pragma("unroll") for (int nf = 0; nf < 4; ++nf) { \
            BG[nf] = *(const i32x4*)&lsG[_b][gro + nf * 1024]; \
            BU[nf] = *(const i32x4*)&lsU[_b][gro + nf * 1024]; } \
    } while (0)

#define STEP_GU(AF, BG, BU, AF2, BG2, BU2, tt) do { \
        wait_vmcnt6(); \
        wait_lgkm0(); \
        barrier_(); \
        STAGE_GU((tt) % 3, ((((tt) + 3) & (NKT - 1)) << 6)); \
        RD_GU(AF2, BG2, BU2, (tt) + 1); \
        _Pragma("unroll") for (int mf = 0; mf < 4; ++mf) \
        _Pragma("unroll") for (int nf = 0; nf < 4; ++nf) { \
            accg[mf][nf] = MFMA_I8(AF[mf], BG[nf], accg[mf][nf], 0, 0, 0); \
            accu[mf][nf] = MFMA_I8(AF[mf], BU[nf], accu[mf][nf], 0, 0, 0); } \
    } while (0)

    const int NKT = H_DIM / 64;  // 64 (power of 2)
    STAGE_GU(0, 0);
    STAGE_GU(1, 64);
    STAGE_GU(2, 128);            // 18 loads in flight per wave
    wait_vmcnt12();              // tile 0 landed
    barrier_();

    i32x4 afA[4], bgA[4], buA[4], afB[4], bgB[4], buB[4];
    RD_GU(afA, bgA, buA, 0);

    for (int t = 0; t < NKT; t += 2) {
        STEP_GU(afA, bgA, buA, afB, bgB, buB, t);
        STEP_GU(afB, bgB, buB, afA, bgA, buA, t + 1);
    }
#undef STEP_GU
#undef RD_GU
#undef STAGE_GU
    wait_vmcnt0();   // drain tail prefetches

    // ---- epilogue: dequant, SwiGLU, requant ----
    const float scale = *scale_p;
#pragma unroll
    for (int nf = 0; nf < 4; ++nf) {
        const int col = n0 + wc * 64 + nf * 16 + lr;
        const float gA = galpha[col], gB = gbias[col];
        const float uA = ualpha[col], uB = ubias[col];
#pragma unroll
        for (int mf = 0; mf < 4; ++mf) {
            const int row0 = m0 + wr * 64 + mf * 16 + (lane >> 4) * 4;
#pragma unroll
            for (int j = 0; j < 4; ++j) {
                float g = (float)accg[mf][nf][j] * gA + gB;
                float u = (float)accu[mf][nf][j] * uA + uB;
                float s = 1.0f / (1.0f + __expf(-g));
                float h = g * s * u;
                float q = rintf(h / scale);
                q = fminf(127.0f, fmaxf(-128.0f, q));
                hq[(size_t)(row0 + j) * I_DIM + col] = (int8_t)q;
            }
        }
    }
}

// ---------------------------------------------------------------------------
// down: BM=256 BN=128 BK=64B, 4 waves (2M x 2N), wave = 128x64. Same pipeline.
// ---------------------------------------------------------------------------
__global__ __launch_bounds__(256, 2)
void down_kernel(const int8_t* __restrict__ hq, const int8_t* __restrict__ dw8,
                 const float* __restrict__ dalpha, const float* __restrict__ dbias,
                 float* __restrict__ out)
{
    __shared__ __align__(16) int8_t lsA[3][256 * 64];
    __shared__ __align__(16) int8_t lsB[3][128 * 64];

    const int bid = blockIdx.x;
    const int mt = bid & 15;                   // 16 M tiles (256 rows)
    const int nt = bid >> 4;                   // 32 N tiles (128 cols)
    const int m0 = mt << 8;
    const int n0 = nt << 7;

    const int tid  = threadIdx.x;
    const int lane = tid & 63;
    const int wid  = tid >> 6;
    const int wr   = wid >> 1;
    const int wc   = wid & 1;
    const int lr   = lane & 15;
    const int rdsw = ((lane >> 4) ^ ((lr >> 1) & 3)) << 4;

    const int srow = tid >> 2;
    const int scol = ((tid & 3) ^ ((tid >> 3) & 3)) << 4;
    const int woff = wid << 10;

    const int8_t* Ap = hq  + (size_t)(m0 + srow) * I_DIM + scol;
    const int8_t* Bp = dw8 + (size_t)(n0 + srow) * I_DIM + scol;

    i32x4 acc[8][4];
#pragma unroll
    for (int mf = 0; mf < 8; ++mf)
#pragma unroll
        for (int nf = 0; nf < 4; ++nf) acc[mf][nf] = i32x4{0, 0, 0, 0};

    const int aro = (wr * 128 + lr) * 64 + rdsw;   // + mf*1024, mf=0..7
    const int bro = (wc * 64 + lr) * 64 + rdsw;    // + nf*1024, nf=0..3

#define STAGE_D(b, kb) do { \
        gload_lds16(Ap + (kb),                         &lsA[b][woff]); \
        gload_lds16(Ap + (kb) + (size_t)64 * I_DIM,    &lsA[b][4096 + woff]); \
        gload_lds16(Ap + (kb) + (size_t)128 * I_DIM,   &lsA[b][8192 + woff]); \
        gload_lds16(Ap + (kb) + (size_t)192 * I_DIM,   &lsA[b][12288 + woff]); \
        gload_lds16(Bp + (kb),                         &lsB[b][woff]); \
        gload_lds16(Bp + (kb) + (size_t)64 * I_DIM,    &lsB[b][4096 + woff]); \
    } while (0)

#define RD_D(AF, BF, tt) do { \
        const int _b = (tt) % 3; \
        _Pragma("unroll") for (int mf = 0; mf < 8; ++mf) \
            AF[mf] = *(const i32x4*)&lsA[_b][aro + mf * 1024]; \
        _Pragma("unroll") for (int nf = 0; nf < 4; ++nf) \
            BF[nf] = *(const i32x4*)&lsB[_b][bro + nf * 1024]; \
    } while (0)

#define STEP_D(AF, BF, AF2, BF2, tt) do { \
        wait_vmcnt6(); \
        wait_lgkm0(); \
        barrier_(); \
        { const int _t3 = ((tt) + 3) % NKT; STAGE_D((tt) % 3, _t3 << 6); } \
        RD_D(AF2, BF2, (tt) + 1); \
        _Pragma("unroll") for (int mf = 0; mf < 8; ++mf) \
        _Pragma("unroll") for (int nf = 0; nf < 4; ++nf) \
            acc[mf][nf] = MFMA_I8(AF[mf], BF[nf], acc[mf][nf], 0, 0, 0); \
    } while (0)

    const int NKT = I_DIM / 64;  // 172 (even)
    STAGE_D(0, 0);
    STAGE_D(1, 64);
    STAGE_D(2, 128);
    wait_vmcnt12();
    barrier_();

    i32x4 afA[8], bfA[4], afB[8], bfB[4];
    RD_D(afA, bfA, 0);

    for (int t = 0; t < NKT; t += 2) {
        STEP_D(afA, bfA, afB, bfB, t);
        STEP_D(afB, bfB, afA, bfA, t + 1);
    }
#undef STEP_D
#undef RD_D
#undef STAGE_D
    wait_vmcnt0();

    // ---- epilogue: dequant to fp32 ----
#pragma unroll
    for (int nf = 0; nf < 4; ++nf) {
        const int col = n0 + wc * 64 + nf * 16 + lr;
        const float dA = dalpha[col], dB = dbias[col];
#pragma unroll
        for (int mf = 0; mf < 8; ++mf) {
            const int row0 = m0 + wr * 128 + mf * 16 + (lane >> 4) * 4;
#pragma unroll
            for (int j = 0; j < 4; ++j) {
                out[(size_t)(row0 + j) * H_DIM + col] = (float)acc[mf][nf][j] * dA + dB;
            }
        }
    }
}

extern "C" void kernel_launch(void* const* d_in, const int* in_sizes, int n_in,
                              void* d_out, int out_size, void* d_ws, size_t ws_size,
                              hipStream_t stream) {
    const int* x32  = (const int*)d_in[0];
    const int* gw32 = (const int*)d_in[1];
    const int* uw32 = (const int*)d_in[2];
    const int* dw32 = (const int*)d_in[3];
    const float* ga = (const float*)d_in[4];
    const float* gb = (const float*)d_in[5];
    const float* ua = (const float*)d_in[6];
    const float* ub = (const float*)d_in[7];
    const float* da = (const float*)d_in[8];
    const float* db = (const float*)d_in[9];
    const float* sc = (const float*)d_in[10];
    float* out = (float*)d_out;

    const size_t SZ_X8 = (size_t)T_DIM * H_DIM;
    const size_t SZ_W  = (size_t)I_DIM * H_DIM;
    const size_t SZ_HQ = (size_t)T_DIM * I_DIM;

    int8_t* gw8 = (int8_t*)d_ws;              // reused for dw8 later
    int8_t* uw8 = gw8 + SZ_W;
    int8_t* hq  = uw8 + SZ_W;
    int8_t* x8  = hq + SZ_HQ;

    convert_kernel<<<dim3(2048), dim3(256), 0, stream>>>(x32, x8, (int)(SZ_X8 / 4));
    convert_kernel<<<dim3(2048), dim3(256), 0, stream>>>(gw32, gw8, (int)(SZ_W / 4));
    convert_kernel<<<dim3(2048), dim3(256), 0, stream>>>(uw32, uw8, (int)(SZ_W / 4));
    gateup_kernel<<<dim3(32 * 86), dim3(256), 0, stream>>>(
        x8, gw8, uw8, ga, gb, ua, ub, sc, hq);
    int8_t* dw8 = gw8;   // overwrite gate weights (stream-ordered after gateup)
    convert_kernel<<<dim3(2048), dim3(256), 0, stream>>>(dw32, dw8, (int)(SZ_W / 4));
    down_kernel<<<dim3(16 * 32), dim3(256), 0, stream>>>(hq, dw8, da, db, out);
}

// Round 8
// 693.911 us; speedup vs baseline: 1.0610x; 1.0610x over previous
//
#include <hip/hip_runtime.h>
#include <stdint.h>

#define H_DIM 4096
#define I_DIM 11008
#define T_DIM 4096

typedef int i32x4 __attribute__((ext_vector_type(4)));
typedef const void __attribute__((address_space(1))) gvoid_t;
typedef void __attribute__((address_space(3))) svoid_t;

__device__ __forceinline__ void gload_lds16(const void* gsrc, void* ldst) {
    __builtin_amdgcn_global_load_lds((gvoid_t*)gsrc, (svoid_t*)ldst, 16, 0, 0);
}
__device__ __forceinline__ void wait_vmcnt8() {
    asm volatile("s_waitcnt vmcnt(8)" ::: "memory");
}
__device__ __forceinline__ void wait_vmcnt0() {
    asm volatile("s_waitcnt vmcnt(0)" ::: "memory");
}
__device__ __forceinline__ void barrier_() {
    asm volatile("s_barrier" ::: "memory");
}

__device__ __forceinline__ uint32_t pack4(int4 v) {
    uint32_t r = (uint32_t)(uint8_t)v.x;
    r |= (uint32_t)(uint8_t)v.y << 8;
    r |= (uint32_t)(uint8_t)v.z << 16;
    r |= (uint32_t)(uint8_t)v.w << 24;
    return r;
}

// int32 -> int8 pack (truncate low byte; values already int8-range)
__global__ void convert_kernel(const int* __restrict__ src, int8_t* __restrict__ dst,
                               int n4) {
    int idx = blockIdx.x * blockDim.x + threadIdx.x;
    int stride = gridDim.x * blockDim.x;
    for (int i = idx; i < n4; i += stride) {
        int4 v = ((const int4*)src)[i];
        ((uint32_t*)dst)[i] = pack4(v);
    }
}

#define MFMA_I8 __builtin_amdgcn_mfma_i32_16x16x64_i8

extern __shared__ int8_t smem[];

// ---------------------------------------------------------------------------
// gateup: BM=256, BN=128 (x2 matrices G,U), BK=128B. 512 thr, 8 waves (2Mx4N),
// per-wave 128x32 per matrix. 4 phases/K-tile, 16 MFMA each. kk-half-granular
// staging (1.5-tile lead), vmcnt(8) at P1/P3 only. LDS 128KB dynamic:
// A 4x16KB halves, G 4x8KB, U 4x8KB; 64B rows, XOR-swizzled (2-way max).
// ---------------------------------------------------------------------------
__global__ __launch_bounds__(512, 2)
void gateup_kernel(const int8_t* __restrict__ x8, const int8_t* __restrict__ gw8,
                   const int8_t* __restrict__ uw8,
                   const float* __restrict__ galpha, const float* __restrict__ gbias,
                   const float* __restrict__ ualpha, const float* __restrict__ ubias,
                   const float* __restrict__ scale_p, int8_t* __restrict__ hq)
{
    int8_t* sA = smem;              // 4 halves x 16384
    int8_t* sG = smem + 65536;      // 4 halves x 8192
    int8_t* sU = smem + 98304;      // 4 halves x 8192

    const int bid = blockIdx.x;
    const int mt = bid & 15;        // 16 M tiles of 256 (M fastest: weight L2 reuse)
    const int nt = bid >> 4;        // 86 N tiles of 128
    const int m0 = mt << 8;
    const int n0 = nt << 7;

    const int tid  = threadIdx.x;
    const int lane = tid & 63;
    const int wid  = tid >> 6;
    const int wr   = wid >> 2;      // 0..1
    const int wc   = wid & 3;       // 0..3
    const int lr   = lane & 15;
    const int rdsw = ((lane >> 4) ^ ((lr >> 1) & 3)) << 4;

    // staging: one call = 512 thr x 16B = 128 rows x 64B (pre-swizzled source)
    const int srow  = tid >> 2;                          // 0..127
    const int sslot = ((tid & 3) ^ ((tid >> 3) & 3)) << 4;
    const int woff  = wid << 10;

    const int8_t* As = x8  + (size_t)(m0 + srow) * H_DIM + sslot;
    const int8_t* Gs = gw8 + (size_t)(n0 + srow) * H_DIM + sslot;
    const int8_t* Us = uw8 + (size_t)(n0 + srow) * H_DIM + sslot;

    i32x4 accg[8][2], accu[8][2];
#pragma unroll
    for (int mf = 0; mf < 8; ++mf)
#pragma unroll
        for (int nf = 0; nf < 2; ++nf) {
            accg[mf][nf] = i32x4{0, 0, 0, 0};
            accu[mf][nf] = i32x4{0, 0, 0, 0};
        }

    const int arb = (wr * 128 + lr) * 64 + rdsw;   // + mf*1024 + h*16384
    const int grb = (wc * 32 + lr) * 64 + rdsw;    // + nf*1024 + h*8192

#define STG_A(h, kb, c) gload_lds16(As + (size_t)(c) * 128 * H_DIM + (kb), \
                                    sA + (h) * 16384 + (c) * 8192 + woff)
#define STG_G(h, kb)    gload_lds16(Gs + (kb), sG + (h) * 8192 + woff)
#define STG_U(h, kb)    gload_lds16(Us + (kb), sU + (h) * 8192 + woff)

    const int NKT = H_DIM / 128;    // 32
    // prologue: units (t0,kk0)->h0, (t0,kk1)->h1, (t1,kk0)->h2
    STG_A(0, 0, 0);   STG_A(0, 0, 1);   STG_G(0, 0);   STG_U(0, 0);
    STG_A(1, 64, 0);  STG_A(1, 64, 1);  STG_G(1, 64);  STG_U(1, 64);
    STG_A(2, 128, 0); STG_A(2, 128, 1); STG_G(2, 128); STG_U(2, 128);
    wait_vmcnt8();                  // unit0 (t0,kk0) landed
    barrier_();

    for (int t = 0; t < NKT; ++t) {
        const int h0  = (2 * t) & 3;
        const int h1  = (2 * t + 1) & 3;
        const int hs1 = (2 * t + 3) & 3;                 // dest for (t+1,kk1)
        const int kb1 = ((t + 1) % NKT) * 128 + 64;
        const int kb0 = ((t + 2) % NKT) * 128;
        i32x4 af[4], gf[2], uf[2];

        // ---- P0: kk0, mf0-3 ----
#pragma unroll
        for (int mf = 0; mf < 4; ++mf)
            af[mf] = *(const i32x4*)(sA + h0 * 16384 + arb + mf * 1024);
#pragma unroll
        for (int nf = 0; nf < 2; ++nf) {
            gf[nf] = *(const i32x4*)(sG + h0 * 8192 + grb + nf * 1024);
            uf[nf] = *(const i32x4*)(sU + h0 * 8192 + grb + nf * 1024);
        }
        STG_A(hs1, kb1, 0); STG_A(hs1, kb1, 1);
        barrier_();
        __builtin_amdgcn_s_setprio(1);
#pragma unroll
        for (int mf = 0; mf < 4; ++mf)
#pragma unroll
            for (int nf = 0; nf < 2; ++nf) {
                accg[mf][nf] = MFMA_I8(af[mf], gf[nf], accg[mf][nf], 0, 0, 0);
                accu[mf][nf] = MFMA_I8(af[mf], uf[nf], accu[mf][nf], 0, 0, 0);
            }
        __builtin_amdgcn_s_setprio(0);
        barrier_();

        // ---- P1: kk0, mf4-7 (reuse gf, uf) ----
#pragma unroll
        for (int mf = 0; mf < 4; ++mf)
            af[mf] = *(const i32x4*)(sA + h0 * 16384 + arb + (mf + 4) * 1024);
        STG_G(hs1, kb1); STG_U(hs1, kb1);
        wait_vmcnt8();              // certify (t,kk1) for P2
        barrier_();
        __builtin_amdgcn_s_setprio(1);
#pragma unroll
        for (int mf = 0; mf < 4; ++mf)
#pragma unroll
            for (int nf = 0; nf < 2; ++nf) {
                accg[mf + 4][nf] = MFMA_I8(af[mf], gf[nf], accg[mf + 4][nf], 0, 0, 0);
                accu[mf + 4][nf] = MFMA_I8(af[mf], uf[nf], accu[mf + 4][nf], 0, 0, 0);
            }
        __builtin_amdgcn_s_setprio(0);
        barrier_();

        // ---- P2: kk1, mf0-3 ----
#pragma unroll
        for (int mf = 0; mf < 4; ++mf)
            af[mf] = *(const i32x4*)(sA + h1 * 16384 + arb + mf * 1024);
#pragma unroll
        for (int nf = 0; nf < 2; ++nf) {
            gf[nf] = *(const i32x4*)(sG + h1 * 8192 + grb + nf * 1024);
            uf[nf] = *(const i32x4*)(sU + h1 * 8192 + grb + nf * 1024);
        }
        STG_A(h0, kb0, 0); STG_A(h0, kb0, 1);   // (t+2,kk0) -> h0 (freed after P1)
        barrier_();
        __builtin_amdgcn_s_setprio(1);
#pragma unroll
        for (int mf = 0; mf < 4; ++mf)
#pragma unroll
            for (int nf = 0; nf < 2; ++nf) {
                accg[mf][nf] = MFMA_I8(af[mf], gf[nf], accg[mf][nf], 0, 0, 0);
                accu[mf][nf] = MFMA_I8(af[mf], uf[nf], accu[mf][nf], 0, 0, 0);
            }
        __builtin_amdgcn_s_setprio(0);
        barrier_();

        // ---- P3: kk1, mf4-7 ----
#pragma unroll
        for (int mf = 0; mf < 4; ++mf)
            af[mf] = *(const i32x4*)(sA + h1 * 16384 + arb + (mf + 4) * 1024);
        STG_G(h0, kb0); STG_U(h0, kb0);
        wait_vmcnt8();              // certify (t+1,kk0) for next P0
        barrier_();
        __builtin_amdgcn_s_setprio(1);
#pragma unroll
        for (int mf = 0; mf < 4; ++mf)
#pragma unroll
            for (int nf = 0; nf < 2; ++nf) {
                accg[mf + 4][nf] = MFMA_I8(af[mf], gf[nf], accg[mf + 4][nf], 0, 0, 0);
                accu[mf + 4][nf] = MFMA_I8(af[mf], uf[nf], accu[mf + 4][nf], 0, 0, 0);
            }
        __builtin_amdgcn_s_setprio(0);
        barrier_();
    }
#undef STG_A
#undef STG_G
#undef STG_U
    wait_vmcnt0();

    // ---- epilogue: dequant, SwiGLU, requant (R3-verified mapping) ----
    const float scale = *scale_p;
#pragma unroll
    for (int nf = 0; nf < 2; ++nf) {
        const int col = n0 + wc * 32 + nf * 16 + lr;
        const float gA = galpha[col], gB = gbias[col];
        const float uA = ualpha[col], uB = ubias[col];
#pragma unroll
        for (int mf = 0; mf < 8; ++mf) {
            const int row0 = m0 + wr * 128 + mf * 16 + (lane >> 4) * 4;
#pragma unroll
            for (int j = 0; j < 4; ++j) {
                float g = (float)accg[mf][nf][j] * gA + gB;
                float u = (float)accu[mf][nf][j] * uA + uB;
                float s = 1.0f / (1.0f + __expf(-g));
                float h = g * s * u;
                float q = rintf(h / scale);
                q = fminf(127.0f, fmaxf(-128.0f, q));
                hq[(size_t)(row0 + j) * I_DIM + col] = (int8_t)q;
            }
        }
    }
}

// ---------------------------------------------------------------------------
// down: BM=256, BN=256, BK=128B. 8 waves (2Mx4N), per-wave 128x64. Same
// 4-phase schedule. LDS: A 4x16KB + B 4x16KB = 128KB.
// ---------------------------------------------------------------------------
__global__ __launch_bounds__(512, 2)
void down_kernel(const int8_t* __restrict__ hq, const int8_t* __restrict__ dw8,
                 const float* __restrict__ dalpha, const float* __restrict__ dbias,
                 float* __restrict__ out)
{
    int8_t* sA = smem;              // 4 halves x 16384
    int8_t* sB = smem + 65536;      // 4 halves x 16384

    const int bid = blockIdx.x;
    const int mt = bid & 15;        // 16 M tiles of 256
    const int nt = bid >> 4;        // 16 N tiles of 256
    const int m0 = mt << 8;
    const int n0 = nt << 8;

    const int tid  = threadIdx.x;
    const int lane = tid & 63;
    const int wid  = tid >> 6;
    const int wr   = wid >> 2;
    const int wc   = wid & 3;
    const int lr   = lane & 15;
    const int rdsw = ((lane >> 4) ^ ((lr >> 1) & 3)) << 4;

    const int srow  = tid >> 2;
    const int sslot = ((tid & 3) ^ ((tid >> 3) & 3)) << 4;
    const int woff  = wid << 10;

    const int8_t* Ap = hq  + (size_t)(m0 + srow) * I_DIM + sslot;
    const int8_t* Bp = dw8 + (size_t)(n0 + srow) * I_DIM + sslot;

    i32x4 acc[8][4];
#pragma unroll
    for (int mf = 0; mf < 8; ++mf)
#pragma unroll
        for (int nf = 0; nf < 4; ++nf) acc[mf][nf] = i32x4{0, 0, 0, 0};

    const int arb = (wr * 128 + lr) * 64 + rdsw;   // + mf*1024 + h*16384
    const int brb = (wc * 64 + lr) * 64 + rdsw;    // + nf*1024 + h*16384

#define STG_A(h, kb, c) gload_lds16(Ap + (size_t)(c) * 128 * I_DIM + (kb), \
                                    sA + (h) * 16384 + (c) * 8192 + woff)
#define STG_B(h, kb, c) gload_lds16(Bp + (size_t)(c) * 128 * I_DIM + (kb), \
                                    sB + (h) * 16384 + (c) * 8192 + woff)

    const int NKT = I_DIM / 128;    // 86
    STG_A(0, 0, 0);   STG_A(0, 0, 1);   STG_B(0, 0, 0);   STG_B(0, 0, 1);
    STG_A(1, 64, 0);  STG_A(1, 64, 1);  STG_B(1, 64, 0);  STG_B(1, 64, 1);
    STG_A(2, 128, 0); STG_A(2, 128, 1); STG_B(2, 128, 0); STG_B(2, 128, 1);
    wait_vmcnt8();
    barrier_();

    for (int t = 0; t < NKT; ++t) {
        const int h0  = (2 * t) & 3;
        const int h1  = (2 * t + 1) & 3;
        const int hs1 = (2 * t + 3) & 3;
        const int kb1 = ((t + 1) % NKT) * 128 + 64;
        const int kb0 = ((t + 2) % NKT) * 128;
        i32x4 af[4], bf[4];

        // ---- P0: kk0, mf0-3 x nf0-3 ----
#pragma unroll
        for (int mf = 0; mf < 4; ++mf)
            af[mf] = *(const i32x4*)(sA + h0 * 16384 + arb + mf * 1024);
#pragma unroll
        for (int nf = 0; nf < 4; ++nf)
            bf[nf] = *(const i32x4*)(sB + h0 * 16384 + brb + nf * 1024);
        STG_A(hs1, kb1, 0); STG_A(hs1, kb1, 1);
        barrier_();
        __builtin_amdgcn_s_setprio(1);
#pragma unroll
        for (int mf = 0; mf < 4; ++mf)
#pragma unroll
            for (int nf = 0; nf < 4; ++nf)
                acc[mf][nf] = MFMA_I8(af[mf], bf[nf], acc[mf][nf], 0, 0, 0);
        __builtin_amdgcn_s_setprio(0);
        barrier_();

        // ---- P1: kk0, mf4-7 (reuse bf) ----
#pragma unroll
        for (int mf = 0; mf < 4; ++mf)
            af[mf] = *(const i32x4*)(sA + h0 * 16384 + arb + (mf + 4) * 1024);
        STG_B(hs1, kb1, 0); STG_B(hs1, kb1, 1);
        wait_vmcnt8();
        barrier_();
        __builtin_amdgcn_s_setprio(1);
#pragma unroll
        for (int mf = 0; mf < 4; ++mf)
#pragma unroll
            for (int nf = 0; nf < 4; ++nf)
                acc[mf + 4][nf] = MFMA_I8(af[mf], bf[nf], acc[mf + 4][nf], 0, 0, 0);
        __builtin_amdgcn_s_setprio(0);
        barrier_();

        // ---- P2: kk1, mf0-3 ----
#pragma unroll
        for (int mf = 0; mf < 4; ++mf)
            af[mf] = *(const i32x4*)(sA + h1 * 16384 + arb + mf * 1024);
#pragma unroll
        for (int nf = 0; nf < 4; ++nf)
            bf[nf] = *(const i32x4*)(sB + h1 * 16384 + brb + nf * 1024);
        STG_A(h0, kb0, 0); STG_A(h0, kb0, 1);
        barrier_();
        __builtin_amdgcn_s_setprio(1);
#pragma unroll
        for (int mf = 0; mf < 4; ++mf)
#pragma unroll
            for (int nf = 0; nf < 4; ++nf)
                acc[mf][nf] = MFMA_I8(af[mf], bf[nf], acc[mf][nf], 0, 0, 0);
        __builtin_amdgcn_s_setprio(0);
        barrier_();

        // ---- P3: kk1, mf4-7 ----
#pragma unroll
        for (int mf = 0; mf < 4; ++mf)
            af[mf] = *(const i32x4*)(sA + h1 * 16384 + arb + (mf + 4) * 1024);
        STG_B(h0, kb0, 0); STG_B(h0, kb0, 1);
        wait_vmcnt8();
        barrier_();
        __builtin_amdgcn_s_setprio(1);
#pragma unroll
        for (int mf = 0; mf < 4; ++mf)
#pragma unroll
            for (int nf = 0; nf < 4; ++nf)
                acc[mf + 4][nf] = MFMA_I8(af[mf], bf[nf], acc[mf + 4][nf], 0, 0, 0);
        __builtin_amdgcn_s_setprio(0);
        barrier_();
    }
#undef STG_A
#undef STG_B
    wait_vmcnt0();

    // ---- epilogue: dequant to fp32 (R3-verified mapping) ----
#pragma unroll
    for (int nf = 0; nf < 4; ++nf) {
        const int col = n0 + wc * 64 + nf * 16 + lr;
        const float dA = dalpha[col], dB = dbias[col];
#pragma unroll
        for (int mf = 0; mf < 8; ++mf) {
            const int row0 = m0 + wr * 128 + mf * 16 + (lane >> 4) * 4;
#pragma unroll
            for (int j = 0; j < 4; ++j) {
                out[(size_t)(row0 + j) * H_DIM + col] = (float)acc[mf][nf][j] * dA + dB;
            }
        }
    }
}

extern "C" void kernel_launch(void* const* d_in, const int* in_sizes, int n_in,
                              void* d_out, int out_size, void* d_ws, size_t ws_size,
                              hipStream_t stream) {
    const int* x32  = (const int*)d_in[0];
    const int* gw32 = (const int*)d_in[1];
    const int* uw32 = (const int*)d_in[2];
    const int* dw32 = (const int*)d_in[3];
    const float* ga = (const float*)d_in[4];
    const float* gb = (const float*)d_in[5];
    const float* ua = (const float*)d_in[6];
    const float* ub = (const float*)d_in[7];
    const float* da = (const float*)d_in[8];
    const float* db = (const float*)d_in[9];
    const float* sc = (const float*)d_in[10];
    float* out = (float*)d_out;

    const size_t SZ_X8 = (size_t)T_DIM * H_DIM;
    const size_t SZ_W  = (size_t)I_DIM * H_DIM;
    const size_t SZ_HQ = (size_t)T_DIM * I_DIM;

    int8_t* gw8 = (int8_t*)d_ws;              // reused for dw8 later
    int8_t* uw8 = gw8 + SZ_W;
    int8_t* hq  = uw8 + SZ_W;
    int8_t* x8  = hq + SZ_HQ;

    hipFuncSetAttribute((const void*)gateup_kernel,
                        hipFuncAttributeMaxDynamicSharedMemorySize, 131072);
    hipFuncSetAttribute((const void*)down_kernel,
                        hipFuncAttributeMaxDynamicSharedMemorySize, 131072);

    convert_kernel<<<dim3(2048), dim3(256), 0, stream>>>(x32, x8, (int)(SZ_X8 / 4));
    convert_kernel<<<dim3(2048), dim3(256), 0, stream>>>(gw32, gw8, (int)(SZ_W / 4));
    convert_kernel<<<dim3(2048), dim3(256), 0, stream>>>(uw32, uw8, (int)(SZ_W / 4));
    gateup_kernel<<<dim3(16 * 86), dim3(512), 131072, stream>>>(
        x8, gw8, uw8, ga, gb, ua, ub, sc, hq);
    int8_t* dw8 = gw8;   // overwrite gate weights (stream-ordered after gateup)
    convert_kernel<<<dim3(2048), dim3(256), 0, stream>>>(dw32, dw8, (int)(SZ_W / 4));
    down_kernel<<<dim3(16 * 16), dim3(512), 131072, stream>>>(hq, dw8, da, db, out);
}